// Round 18
// baseline (284.147 us; speedup 1.0000x reference)
//
#include <hip/hip_runtime.h>
#include <hip/hip_fp16.h>

#define CC 256
#define HWIMG 4096
#define NPIX 131072
#define KCODES 1024
#define PAIRCAP 32768
#define FULLCAP 8192
#define KMARGIN 0.0625f   // key-space margin <=> distance margin 0.125

typedef _Float16 half8 __attribute__((ext_vector_type(8)));
typedef short short8v __attribute__((ext_vector_type(8)));
typedef float f32x4 __attribute__((ext_vector_type(4)));
typedef unsigned short u16;
typedef unsigned int u32;

__device__ __forceinline__ void gld16(const void* g, void* l) {
    __builtin_amdgcn_global_load_lds(
        (const __attribute__((address_space(1))) void*)g,
        (__attribute__((address_space(3))) void*)l, 16, 0, 0);
}

// e image: [pass 4][cpair 4][256 rows][128B]; row = code&255; 8 slots of 16B;
// slot = b*4+kg covers ch cpair*64+b*32+kg*8; phys slot = slot ^ (row & 7).

// ---------- prep_e: codebook -> fp16 pair-images + (-esq/2) + zero counters --
__global__ __launch_bounds__(256) void prep_e(const float* __restrict__ cb,
    char* __restrict__ e_prep, float* __restrict__ esq, int* __restrict__ cnts)
{
    __shared__ u16 eh[256];
    __shared__ float red[4];
    int k = blockIdx.x, c = threadIdx.x;
    float v = cb[(size_t)k * CC + c];
    eh[c] = __half_as_ushort(__float2half(v));
    float s = v * v;
    #pragma unroll
    for (int m = 32; m; m >>= 1) s += __shfl_xor(s, m, 64);
    if ((c & 63) == 0) red[c >> 6] = s;
    __syncthreads();
    if (c == 0) {
        esq[k] = -0.5f * ((red[0] + red[1]) + (red[2] + red[3]));
        if (k == 0) { cnts[0] = 0; cnts[1] = 0; }
    }
    if (c < 32) {                       // 4 channel-pairs (cpair) x 8 phys slots
        int cpair = c >> 3, phys = c & 7;
        int pass = k >> 8, row = k & 255;
        int slot = phys ^ (row & 7);
        int cst = cpair * 64 + (slot >> 2) * 32 + (slot & 3) * 8;
        short8v w;
        #pragma unroll
        for (int j = 0; j < 8; ++j) w[j] = (short)eh[cst + j];
        *(short8v*)(e_prep + (size_t)(pass * 4 + cpair) * 32768 + row * 128 + phys * 16) = w;
    }
}

// ---------- prep_xT: x NCHW fp32 -> fp16 frag-major image (d_out) + xsq ------
__global__ __launch_bounds__(256) void prep_xT(const float* __restrict__ x,
    char* __restrict__ x_frag, float* __restrict__ xsq)
{
    __shared__ u32 pk[64 * 261];      // [px][c] fp16 in low bits
    __shared__ float xsq_p[256];
    const int blk = blockIdx.x, t = threadIdx.x;
    const float* xb = x + (size_t)(blk >> 6) * (CC * HWIMG) + (blk & 63) * 64;
    #pragma unroll 4
    for (int p = 0; p < 16; ++p) {
        int c = p * 16 + (t >> 4);
        int px4 = (t & 15) * 4;
        float4 v = *(const float4*)&xb[(size_t)c * HWIMG + px4];
        float vv[4] = {v.x, v.y, v.z, v.w};
        #pragma unroll
        for (int i = 0; i < 4; ++i)
            pk[(px4 + i) * 261 + c] = (u32)__half_as_ushort(__float2half(vv[i]));
    }
    __syncthreads();
    {
        int px = t & 63, qr = t >> 6;
        const u32* pr = &pk[px * 261 + qr * 64];
        float s = 0.f;
        #pragma unroll 4
        for (int c = 0; c < 64; ++c) {
            float h = __half2float(__ushort_as_half((u16)pr[c]));
            s = fmaf(h, h, s);
        }
        xsq_p[t] = s;
    }
    char* obase = x_frag + (size_t)blk * 32768;
    #pragma unroll
    for (int i = 0; i < 8; ++i) {
        int gid = t + 256 * i;            // [f 4][kc 8][l 64]
        int l = gid & 63;
        int kc = (gid >> 6) & 7, f = gid >> 9;
        int px = f * 16 + (l & 15);
        int c0 = kc * 32 + (l >> 4) * 8;
        const u32* pr = &pk[px * 261 + c0];
        short8v ov;
        #pragma unroll
        for (int j = 0; j < 8; ++j) ov[j] = (short)(pr[j] & 0xFFFF);
        *(short8v*)(obase + gid * 16) = ov;
    }
    __syncthreads();
    if (t < 64)
        xsq[blk * 64 + t] = (xsq_p[t] + xsq_p[t + 64]) + (xsq_p[t + 128] + xsq_p[t + 192]);
}

// ---------- dist: x-stationary swapped-operand MFMA; branch-free top-3 -------
__global__ __launch_bounds__(256, 2) void dist_kernel(
    const char* __restrict__ x_frag, const char* __restrict__ e_prep,
    const float* __restrict__ esq_g,
    int* __restrict__ min_idx, float* __restrict__ min_d,
    int* __restrict__ cnts, int2* __restrict__ pair_list,
    int* __restrict__ full_list)
{
    __shared__ char smem[69632];          // 2 x 32KB e dbuf | 4KB (-esq/2)
    char* esql = smem + 65536;

    const int t = threadIdx.x;
    const int l = t & 63;
    const int wid = t >> 6;
    const int lrow = l & 15;
    const int kg   = l >> 4;
    const int ph0  = ((kg    ) ^ (lrow & 7)) * 16 + lrow * 128;
    const int ph1  = ((kg ^ 4) ^ (lrow & 7)) * 16 + lrow * 128;
    const int pxbase = blockIdx.x * 256 + wid * 64;

    half8 Xreg[4][8];
    #pragma unroll
    for (int f = 0; f < 4; ++f)
        #pragma unroll
        for (int kc = 0; kc < 8; ++kc)
            Xreg[f][kc] = *(const half8*)(x_frag +
                (size_t)(((pxbase >> 4) + f) * 8 + kc) * 1024 + l * 16);
    #pragma unroll
    for (int f = 0; f < 4; ++f)
        #pragma unroll
        for (int kc = 0; kc < 8; ++kc)
            asm volatile("" : "+v"(Xreg[f][kc]));

    gld16(esq_g + wid * 256 + l * 4, esql + wid * 1024);

#define STAGE(cur_, tc_) do {                                                  \
        const char* ee_ = e_prep + (size_t)((tc_) >> 2) * 131072               \
                          + ((tc_) & 3) * 8192 + wid * 32768;                  \
        char* bb_ = smem + (cur_) * 32768 + wid * 8192;                        \
        _Pragma("unroll")                                                      \
        for (int i_ = 0; i_ < 8; ++i_)                                         \
            gld16(ee_ + i_ * 1024 + l * 16, bb_ + i_ * 1024);                  \
    } while (0)

    STAGE(0, 0);
    STAGE(1, 1);

    float m1s[4], m2s[4], m3s[4]; int i1s[4], i2s[4];
    #pragma unroll
    for (int f = 0; f < 4; ++f) {
        m1s[f] = -3.4e38f; m2s[f] = -3.4e38f; m3s[f] = -3.4e38f;
        i1s[f] = 0; i2s[f] = 0;
    }

    for (int tc = 0; tc < 16; ++tc) {
        const int cur = tc & 1;
        if (tc == 15) asm volatile("s_waitcnt vmcnt(0)" ::: "memory");
        else          asm volatile("s_waitcnt vmcnt(8)" ::: "memory");
        __builtin_amdgcn_s_barrier();
        __builtin_amdgcn_sched_barrier(0);

        const char* eL = smem + cur * 32768;

        f32x4 acc[4][4];
        #pragma unroll
        for (int mq = 0; mq < 4; ++mq) {
            float4 e4 = *(const float4*)(esql + (tc * 64 + mq * 16 + kg * 4) * 4);
            #pragma unroll
            for (int f = 0; f < 4; ++f)
                acc[mq][f] = (f32x4){e4.x, e4.y, e4.z, e4.w};
        }

        #pragma unroll
        for (int kc = 0; kc < 8; ++kc) {
            const int po = (kc >> 1) * 8192 + ((kc & 1) ? ph1 : ph0);
            half8 A[4];
            #pragma unroll
            for (int mq = 0; mq < 4; ++mq)
                A[mq] = *(const half8*)(eL + po + mq * 2048);
            #pragma unroll
            for (int mq = 0; mq < 4; ++mq)
                #pragma unroll
                for (int f = 0; f < 4; ++f)
                    acc[mq][f] = __builtin_amdgcn_mfma_f32_16x16x32_f16(
                        A[mq], Xreg[f][kc], acc[mq][f], 0, 0, 0);
        }

        // epilogue: branch-free in-lane top-3 over max-keys
        #pragma unroll
        for (int mq = 0; mq < 4; ++mq) {
            const int cb0 = tc * 64 + mq * 16 + kg * 4;
            #pragma unroll
            for (int f = 0; f < 4; ++f) {
                #pragma unroll
                for (int q = 0; q < 4; ++q) {
                    float a = acc[mq][f][q];
                    float o1 = m1s[f], o2 = m2s[f];
                    bool gt1 = a > o1;
                    bool gt2 = a > o2;
                    m3s[f] = __builtin_amdgcn_fmed3f(a, o2, m3s[f]);
                    m2s[f] = __builtin_amdgcn_fmed3f(a, o1, o2);
                    m1s[f] = fmaxf(o1, a);
                    i2s[f] = gt1 ? i1s[f] : (gt2 ? (cb0 + q) : i2s[f]);
                    i1s[f] = gt1 ? (cb0 + q) : i1s[f];
                }
            }
        }
        __builtin_amdgcn_sched_barrier(0);
        __builtin_amdgcn_s_barrier();
        if (tc < 14) STAGE(cur, tc + 2);
    }
#undef STAGE

    // final: merge sorted triples across the 4 kg-lanes per pixel
    #pragma unroll
    for (int f = 0; f < 4; ++f) {
        float a1 = m1s[f], a2 = m2s[f], a3 = m3s[f];
        int ia1 = i1s[f], ia2 = i2s[f];
        #pragma unroll
        for (int msk = 16; msk <= 32; msk <<= 1) {
            float b1 = __shfl_xor(a1, msk, 64);
            float b2 = __shfl_xor(a2, msk, 64);
            float b3 = __shfl_xor(a3, msk, 64);
            int  ib1 = __shfl_xor(ia1, msk, 64);
            int  ib2 = __shfl_xor(ia2, msk, 64);
            if (b1 > a1 || (b1 == a1 && ib1 < ia1)) {
                float tv; int ti;
                tv = a1; a1 = b1; b1 = tv;  ti = ia1; ia1 = ib1; ib1 = ti;
                tv = a2; a2 = b2; b2 = tv;  ti = ia2; ia2 = ib2; ib2 = ti;
                tv = a3; a3 = b3; b3 = tv;
            }
            if (b1 > a2 || (b1 == a2 && ib1 < ia2)) {
                a3 = fmaxf(a2, b2);
                a2 = b1; ia2 = ib1;
            } else {
                a3 = fmaxf(a3, b1);
            }
        }
        if (kg == 0) {
            int n = pxbase + f * 16 + lrow;
            min_idx[n] = ia1;
            min_d[n] = -2.0f * a1;
            if (a1 - a3 <= KMARGIN) {           // >=3 candidates: full sweep
                int slot = atomicAdd(&cnts[1], 1);
                if (slot < FULLCAP) full_list[slot] = n;
            } else if (a1 - a2 <= KMARGIN) {    // exactly 2: fp64 pair check
                int slot = atomicAdd(&cnts[0], 1);
                if (slot < PAIRCAP) pair_list[slot] = make_int2(n, (ia1 << 16) | ia2);
            }
        }
    }
}

// ---------- recheck_pair: fp64 compare of two candidates, 1 wave/pixel -------
__global__ __launch_bounds__(256) void recheck_pair(
    const float* __restrict__ x, const float* __restrict__ cb,
    const int* __restrict__ cnts, const int2* __restrict__ pair_list,
    int* __restrict__ min_idx, float* __restrict__ min_d,
    const float* __restrict__ xsq)
{
    int cnt = cnts[0]; if (cnt > PAIRCAP) cnt = PAIRCAP;
    const int l = threadIdx.x & 63;
    const int w = blockIdx.x * 4 + (threadIdx.x >> 6);
    for (int f = w; f < cnt; f += gridDim.x * 4) {
        int2 pr = pair_list[f];
        int n = pr.x, i1 = pr.y >> 16, i2 = pr.y & 0xFFFF;
        int b = n >> 12, hw = n & 4095;
        const float* xb = x + (size_t)b * CC * HWIMG + hw;
        float4 e1 = *(const float4*)&cb[(size_t)i1 * CC + l * 4];
        float4 e2 = *(const float4*)&cb[(size_t)i2 * CC + l * 4];
        float e1a[4] = {e1.x, e1.y, e1.z, e1.w};
        float e2a[4] = {e2.x, e2.y, e2.z, e2.w};
        double s1 = 0.0, s2 = 0.0;
        #pragma unroll
        for (int j = 0; j < 4; ++j) {
            double xd = (double)xb[(size_t)(l * 4 + j) * HWIMG];
            double d1 = xd - (double)e1a[j];
            double d2 = xd - (double)e2a[j];
            s1 = fma(d1, d1, s1);
            s2 = fma(d2, d2, s2);
        }
        #pragma unroll
        for (int m = 32; m; m >>= 1) {
            s1 += __shfl_xor(s1, m, 64);
            s2 += __shfl_xor(s2, m, 64);
        }
        if (l == 0) {
            bool sec = (s2 < s1) || (s2 == s1 && i2 < i1);
            min_idx[n] = sec ? i2 : i1;
            double dw = sec ? s2 : s1;
            min_d[n] = (float)(dw - (double)xsq[n]);
        }
    }
}

// ---------- recheck_full4: fp64 exact argmin, 4 flagged pixels per block -----
__global__ __launch_bounds__(256) void recheck_full4(
    const float* __restrict__ x, const float* __restrict__ cb,
    const int* __restrict__ cnts, const int* __restrict__ full_list,
    int* __restrict__ min_idx, float* __restrict__ min_d,
    const float* __restrict__ xsq)
{
    __shared__ float  xs[4][CC];
    __shared__ double rbest[4][256];
    __shared__ int    ribst[4][256];
    int cnt = cnts[1]; if (cnt > FULLCAP) cnt = FULLCAP;
    int ngrp = (cnt + 3) >> 2;
    const int t = threadIdx.x;
    for (int g = blockIdx.x; g < ngrp; g += gridDim.x) {
        int npx = cnt - g * 4; if (npx > 4) npx = 4;
        for (int i = t; i < npx * 256; i += 256) {
            int p = i >> 8, c = i & 255;
            int n = full_list[g * 4 + p];
            int b = n >> 12, hw = n & 4095;
            xs[p][c] = x[(size_t)b * CC * HWIMG + (size_t)c * HWIMG + hw];
        }
        __syncthreads();
        double best[4] = {1e300, 1e300, 1e300, 1e300};
        int bi[4] = {0, 0, 0, 0};
        #pragma unroll
        for (int kk = 0; kk < 4; ++kk) {
            int k = t * 4 + kk;
            const float4* er = (const float4*)(cb + (size_t)k * CC);
            double s[4] = {0.0, 0.0, 0.0, 0.0};
            #pragma unroll 4
            for (int c4 = 0; c4 < 64; ++c4) {
                float4 e = er[c4];
                float ea[4] = {e.x, e.y, e.z, e.w};
                #pragma unroll
                for (int jj = 0; jj < 4; ++jj) {
                    #pragma unroll
                    for (int p = 0; p < 4; ++p) {
                        double d = (double)xs[p][c4 * 4 + jj] - (double)ea[jj];
                        s[p] = fma(d, d, s[p]);
                    }
                }
            }
            #pragma unroll
            for (int p = 0; p < 4; ++p)
                if (s[p] < best[p]) { best[p] = s[p]; bi[p] = k; }
        }
        #pragma unroll
        for (int p = 0; p < 4; ++p) { rbest[p][t] = best[p]; ribst[p][t] = bi[p]; }
        __syncthreads();
        for (int st = 128; st; st >>= 1) {
            if (t < st) {
                #pragma unroll
                for (int p = 0; p < 4; ++p) {
                    double ov = rbest[p][t + st]; int oi = ribst[p][t + st];
                    if (ov < rbest[p][t] || (ov == rbest[p][t] && oi < ribst[p][t])) {
                        rbest[p][t] = ov; ribst[p][t] = oi;
                    }
                }
            }
            __syncthreads();
        }
        if (t < npx) {
            int n = full_list[g * 4 + t];
            min_idx[n] = ribst[t][0];
            min_d[n] = (float)(rbest[t][0] - (double)xsq[n]);
        }
        __syncthreads();
    }
}

// ---------- out: pure gather of quantized rows into NCHW ---------------------
__global__ __launch_bounds__(256) void out_kernel(
    const float* __restrict__ cb, const int* __restrict__ min_idx,
    float* __restrict__ out)
{
    int n = blockIdx.x * 256 + threadIdx.x;
    int b = n >> 12, hw = n & 4095;
    float* ob = out + (size_t)b * CC * HWIMG + hw;
    int k = min_idx[n];
    const float* er = cb + (size_t)k * CC;
    #pragma unroll 8
    for (int c = 0; c < CC; c += 4) {
        float4 q = *(const float4*)&er[c];
        ob[(size_t)(c + 0) * HWIMG] = q.x;
        ob[(size_t)(c + 1) * HWIMG] = q.y;
        ob[(size_t)(c + 2) * HWIMG] = q.z;
        ob[(size_t)(c + 3) * HWIMG] = q.w;
    }
}

// ---------- loss_reduce: sum (min_d + xsq) in fp64 ---------------------------
__global__ __launch_bounds__(256) void loss_reduce(
    const float* __restrict__ min_d, const float* __restrict__ xsq,
    double* __restrict__ partials)
{
    int n = blockIdx.x * 256 + threadIdx.x;
    double v = (double)min_d[n] + (double)xsq[n];
    __shared__ double sred[256];
    sred[threadIdx.x] = v;
    __syncthreads();
    for (int s = 128; s; s >>= 1) {
        if (threadIdx.x < (unsigned)s) sred[threadIdx.x] += sred[threadIdx.x + s];
        __syncthreads();
    }
    if (threadIdx.x == 0) partials[blockIdx.x] = sred[0];
}

__global__ void loss_kernel(const double* __restrict__ partials, float* __restrict__ out)
{
    if (threadIdx.x == 0 && blockIdx.x == 0) {
        double s = 0.0;
        for (int i = 0; i < 512; i++) s += partials[i];
        out[33554432] = (float)(1.25 * s / 33554432.0);
    }
}

// ---------- launch -----------------------------------------------------------
extern "C" void kernel_launch(void* const* d_in, const int* in_sizes, int n_in,
                              void* d_out, int out_size, void* d_ws, size_t ws_size,
                              hipStream_t stream)
{
    const float* x  = (const float*)d_in[0];
    const float* cb = (const float*)d_in[1];
    float* out = (float*)d_out;

    // x_frag (64 MB) lives in d_out; out_kernel rewrites d_out afterwards.
    char* x_frag = (char*)d_out;

    char* ws = (char*)d_ws;
    char*   e_prep    = (char*) (ws + 0);            //   524,288 B
    float*  esq       = (float*)(ws + 524288);       //     4,096 B
    int*    min_idx   = (int*)  (ws + 528384);       //   524,288 B
    int*    cnts      = (int*)  (ws + 1052672);      //        16 B
    int2*   pair_list = (int2*) (ws + 1052688);      //   262,144 B
    int*    full_list = (int*)  (ws + 1314832);      //    32,768 B
    double* partials  = (double*)(ws + 1347600);     //     4,096 B
    float*  min_d     = (float*)(ws + 1351696);      //   524,288 B
    float*  xsq       = (float*)(ws + 1875984);      //   524,288 B

    prep_e       <<<KCODES, 256, 0, stream>>>(cb, e_prep, esq, cnts);
    prep_xT      <<<NPIX / 64, 256, 0, stream>>>(x, x_frag, xsq);
    dist_kernel  <<<512, 256, 0, stream>>>(x_frag, e_prep, esq,
                                           min_idx, min_d, cnts,
                                           pair_list, full_list);
    recheck_pair <<<512, 256, 0, stream>>>(x, cb, cnts, pair_list,
                                           min_idx, min_d, xsq);
    recheck_full4<<<256, 256, 0, stream>>>(x, cb, cnts, full_list,
                                           min_idx, min_d, xsq);
    out_kernel   <<<NPIX / 256, 256, 0, stream>>>(cb, min_idx, out);
    loss_reduce  <<<NPIX / 256, 256, 0, stream>>>(min_d, xsq, partials);
    loss_kernel  <<<1, 64, 0, stream>>>(partials, out);
}